// Round 14
// baseline (425.430 us; speedup 1.0000x reference)
//
#include <hip/hip_runtime.h>
#include <hip/hip_bf16.h>

#define N_NODES 50000
#define N_PAD   50048      // 64-row multiple for guard-free GEMM tiles
#define N_EDGES 800000
#define DF 128
#define NG (N_PAD / 64)    // 782 node-GEMM blocks
#define DEG_BLOCKS (N_EDGES / 256)  // 3125
#define EB 128             // edges per block in edge_fused5

// LDS row stride (ushorts): 128 bf16 + 8 pad (272 B = 17*16 B)
#define HS 136

typedef __bf16 bf16x8 __attribute__((ext_vector_type(8)));
typedef float f32x4 __attribute__((ext_vector_type(4)));
typedef unsigned int uint4v __attribute__((ext_vector_type(4)));
typedef unsigned short us4 __attribute__((ext_vector_type(4)));
typedef unsigned short us8 __attribute__((ext_vector_type(8)));

__device__ __forceinline__ unsigned short f2bf(float f) {
  unsigned u = __builtin_bit_cast(unsigned, f);
  u += 0x7FFFu + ((u >> 16) & 1u);   // RNE
  return (unsigned short)(u >> 16);
}
__device__ __forceinline__ float bf2f(unsigned short u) {
  return __builtin_bit_cast(float, ((unsigned)u) << 16);
}

// Packed-fragment offset for element (k,col) of a [128][128] matrix.
__device__ __forceinline__ int pack_off(int k, int c) {
  return ((((c >> 4) * 4 + (k >> 5)) * 64) + ((k >> 3) & 3) * 16 + (c & 15)) * 8
         + (k & 7);
}

// ---------------- fused weight prep + deg histogram (proven r10) ----------------
__global__ __launch_bounds__(256)
void wprep_deg(const float* __restrict__ W2_0,
               const float* __restrict__ W1_1,
               const float* __restrict__ b2_0,
               const float* __restrict__ W1_0,
               const float* __restrict__ W2_1,
               unsigned short* __restrict__ w20Ap,
               unsigned short* __restrict__ w20Bp,
               float* __restrict__ vA,
               float* __restrict__ vB,
               unsigned short* __restrict__ wa1p,
               unsigned short* __restrict__ wb1p,
               unsigned short* __restrict__ w21p,
               const int* __restrict__ dst,
               int* __restrict__ deg) {
  const int b = blockIdx.x;
  const int t = threadIdx.x;

  if (b < 129) {                      // wcomb, direct-packed
    const int c = t & 127;
    const bool isB = t >= 128;
    float acc = 0.f;
    if (b < 128) {
      const float* wrow = W2_0 + (size_t)b * DF;
      for (int k = 0; k < 128; ++k) {
        float bot = W1_1[(size_t)(128 + k) * DF + c];
        float w = isB ? bot : (W1_1[(size_t)k * DF + c] - bot);
        acc += wrow[k] * w;
      }
      unsigned short* out = isB ? w20Bp : w20Ap;
      out[pack_off(b, c)] = f2bf(acc);
    } else {
      for (int k = 0; k < 128; ++k) {
        float bot = W1_1[(size_t)(128 + k) * DF + c];
        float w = isB ? bot : (W1_1[(size_t)k * DF + c] - bot);
        acc += b2_0[k] * w;
      }
      if (isB) vB[c] = acc;
      else     vA[c] = acc;
    }
    return;
  }

  if (b < 153) {                      // pack wa1p / wb1p / w21p
    const int mat = (b - 129) >> 3;
    const int idx = ((b - 129) & 7) * 256 + t;   // < 2048
    const int l = idx & 63;
    const int blk = idx >> 6;
    const int ct = blk >> 2;
    const int kc = blk & 3;
    const int col = ct * 16 + (l & 15);
    const int k0 = kc * 32 + (l >> 4) * 8;
    const float* W;
    const float* Wsub = nullptr;
    unsigned short* out;
    if (mat == 0)      { W = W1_0;            Wsub = W1_0 + 128 * DF; out = wa1p; }
    else if (mat == 1) { W = W1_0 + 128 * DF;                         out = wb1p; }
    else               { W = W2_1;                                    out = w21p; }
    unsigned short tmp[8];
#pragma unroll
    for (int j = 0; j < 8; ++j) {
      float v = W[(size_t)(k0 + j) * DF + col];
      if (Wsub) v -= Wsub[(size_t)(k0 + j) * DF + col];
      tmp[j] = f2bf(v);
    }
    us4 lo = { tmp[0], tmp[1], tmp[2], tmp[3] };
    us4 hi = { tmp[4], tmp[5], tmp[6], tmp[7] };
    us4* o = (us4*)(out + (size_t)idx * 8);
    o[0] = lo;
    o[1] = hi;
    return;
  }

  // deg histogram
  const int e = (b - 153) * 256 + t;
  if (e < N_EDGES) atomicAdd(&deg[dst[e]], 1);
}

// ---------------- CSR sort: packed (src,eid) + dst (proven r12) ----------------
__global__ void sort_kernel(const int* __restrict__ src,
                            const int* __restrict__ dst,
                            int* __restrict__ cursor,
                            int2* __restrict__ sorted_se,
                            int* __restrict__ sorted_dst) {
  const int e = blockIdx.x * 256 + threadIdx.x;
  const int d = dst[e];
  const int pos = atomicAdd(&cursor[d], 1);
  sorted_se[pos] = make_int2(src[e], e);
  sorted_dst[pos] = d;
}

// ---------------- shared device pieces (proven r12) ----------------
__device__ __forceinline__ void agg_phase(const unsigned short* __restrict__ A,
                                          const unsigned short* __restrict__ B,
                                          const int* __restrict__ row_ptr,
                                          const int2* __restrict__ sorted_se,
                                          unsigned short* xs, int r0, int t) {
  const int w = t >> 6, l = t & 63;
  const int lane16 = l & 15;
  const int g = l >> 4;
#pragma unroll
  for (int i = 0; i < 4; ++i) {
    const int nl = w * 16 + i * 4 + g;       // 0..63
    const int n = r0 + nl;
    const int beg = row_ptr[n];
    const int end = row_ptr[n + 1];
    us8 av = *(const us8*)(A + (size_t)n * DF + lane16 * 8);
    float af[8];
#pragma unroll
    for (int j = 0; j < 8; ++j) af[j] = bf2f(av[j]);
    float acc[8] = {};
    int k = beg;
    for (; k + 8 <= end; k += 8) {
      us8 bv[8];
#pragma unroll
      for (int u = 0; u < 8; ++u) {
        const int s = sorted_se[k + u].x;
        bv[u] = *(const us8*)(B + (size_t)s * DF + lane16 * 8);
      }
#pragma unroll
      for (int j = 0; j < 8; ++j) {
#pragma unroll
        for (int u = 0; u < 8; ++u) {
          float v = af[j] + bf2f(bv[u][j]);
          acc[j] += v > 0.f ? v : 0.f;
        }
      }
    }
    for (; k < end; ++k) {
      const int s = sorted_se[k].x;
      us8 bv = *(const us8*)(B + (size_t)s * DF + lane16 * 8);
#pragma unroll
      for (int j = 0; j < 8; ++j) {
        float v = af[j] + bf2f(bv[j]);
        acc[j] += v > 0.f ? v : 0.f;
      }
    }
    us8 o;
#pragma unroll
    for (int j = 0; j < 8; ++j) o[j] = f2bf(acc[j]);
    *(us8*)&xs[nl * HS + lane16 * 8] = o;
  }
}

// ---------------- kernels ----------------

// Fat kernel: block 0 = scan; blocks 1..NG = layer-1 dual GEMM (proven r10).
#define SCH ((N_PAD + 255) / 256)   // 196
__global__ __launch_bounds__(256)
void scan_gemm1(const int* __restrict__ deg,
                int* __restrict__ row_ptr,
                int* __restrict__ cursor,
                const float* __restrict__ in,
                const unsigned short* __restrict__ wpA,
                const unsigned short* __restrict__ wpB,
                const float* __restrict__ bcA,
                unsigned short* __restrict__ outA,
                unsigned short* __restrict__ outB) {
  __shared__ unsigned short xs[64 * HS];
  const int t = threadIdx.x;

  if (blockIdx.x == 0) {
    int* part = (int*)xs;
    const int lo = t * SCH;
    const int hi = min(lo + SCH, N_PAD);
    int s = 0;
    for (int i = lo; i < hi; ++i) s += deg[i];
    part[t] = s;
    __syncthreads();
    for (int off = 1; off < 256; off <<= 1) {
      int v = (t >= off) ? part[t - off] : 0;
      __syncthreads();
      part[t] += v;
      __syncthreads();
    }
    int run = (t > 0) ? part[t - 1] : 0;
    for (int i = lo; i < hi; ++i) {
      row_ptr[i] = run;
      cursor[i] = run;
      run += deg[i];
    }
    if (t == 255) row_ptr[N_PAD] = part[255];
    return;
  }

  const int r0 = (blockIdx.x - 1) * 64;
  {
    const int e = t >> 2, q = t & 3;
    const int grow = r0 + e;
    const float4* src = (const float4*)(in + (size_t)grow * DF) + q * 8;
#pragma unroll
    for (int i = 0; i < 8; ++i) {
      float4 v = { 0.f, 0.f, 0.f, 0.f };
      if (grow < N_NODES) v = src[i];
      us4 p = { f2bf(v.x), f2bf(v.y), f2bf(v.z), f2bf(v.w) };
      *(us4*)&xs[e * HS + q * 32 + i * 4] = p;
    }
  }
  __syncthreads();

  const int w = t >> 6, l = t & 63, l15 = l & 15, lg = l >> 4;
  f32x4 accA[4][2] = {};
  f32x4 accB[4][2] = {};
  const uint4v* wvA = (const uint4v*)wpA;
  const uint4v* wvB = (const uint4v*)wpB;
#pragma unroll
  for (int kc = 0; kc < 4; ++kc) {
    bf16x8 afr[4];
#pragma unroll
    for (int rt = 0; rt < 4; ++rt)
      afr[rt] = __builtin_bit_cast(bf16x8,
          *(const uint4v*)&xs[(rt * 16 + l15) * HS + kc * 32 + lg * 8]);
#pragma unroll
    for (int c = 0; c < 2; ++c) {
      bf16x8 bfrA = __builtin_bit_cast(bf16x8, wvA[((w * 2 + c) * 4 + kc) * 64 + l]);
      bf16x8 bfrB = __builtin_bit_cast(bf16x8, wvB[((w * 2 + c) * 4 + kc) * 64 + l]);
#pragma unroll
      for (int rt = 0; rt < 4; ++rt) {
        accA[rt][c] = __builtin_amdgcn_mfma_f32_16x16x32_bf16(afr[rt], bfrA, accA[rt][c], 0, 0, 0);
        accB[rt][c] = __builtin_amdgcn_mfma_f32_16x16x32_bf16(afr[rt], bfrB, accB[rt][c], 0, 0, 0);
      }
    }
  }
#pragma unroll
  for (int c = 0; c < 2; ++c) {
    const int col = w * 32 + c * 16 + l15;
    const float cA = bcA[col];
#pragma unroll
    for (int rt = 0; rt < 4; ++rt) {
#pragma unroll
      for (int r = 0; r < 4; ++r) {
        const int grow = r0 + rt * 16 + lg * 4 + r;
        outA[(size_t)grow * DF + col] = f2bf(accA[rt][c][r] + cA);
        outB[(size_t)grow * DF + col] = f2bf(accB[rt][c][r]);
      }
    }
  }
}

// Fused: Hsum1 aggregation (LDS) + combined-weight dual GEMM -> A2, B2 (proven)
__global__ __launch_bounds__(256)
void agg_dual(const unsigned short* __restrict__ A,
              const unsigned short* __restrict__ B,
              const int* __restrict__ row_ptr,
              const int2* __restrict__ sorted_se,
              const unsigned short* __restrict__ wpA,
              const unsigned short* __restrict__ wpB,
              const float* __restrict__ bcA, const float* __restrict__ bdA,
              const float* __restrict__ bdB,
              const int* __restrict__ deg,
              unsigned short* __restrict__ outA,
              unsigned short* __restrict__ outB) {
  __shared__ unsigned short xs[64 * HS];
  const int t = threadIdx.x;
  const int r0 = blockIdx.x * 64;

  agg_phase(A, B, row_ptr, sorted_se, xs, r0, t);
  __syncthreads();

  const int w = t >> 6, l = t & 63, l15 = l & 15, lg = l >> 4;
  f32x4 accA[4][2] = {};
  f32x4 accB[4][2] = {};
  const uint4v* wvA = (const uint4v*)wpA;
  const uint4v* wvB = (const uint4v*)wpB;
#pragma unroll
  for (int kc = 0; kc < 4; ++kc) {
    bf16x8 afr[4];
#pragma unroll
    for (int rt = 0; rt < 4; ++rt)
      afr[rt] = __builtin_bit_cast(bf16x8,
          *(const uint4v*)&xs[(rt * 16 + l15) * HS + kc * 32 + lg * 8]);
#pragma unroll
    for (int c = 0; c < 2; ++c) {
      bf16x8 bfrA = __builtin_bit_cast(bf16x8, wvA[((w * 2 + c) * 4 + kc) * 64 + l]);
      bf16x8 bfrB = __builtin_bit_cast(bf16x8, wvB[((w * 2 + c) * 4 + kc) * 64 + l]);
#pragma unroll
      for (int rt = 0; rt < 4; ++rt) {
        accA[rt][c] = __builtin_amdgcn_mfma_f32_16x16x32_bf16(afr[rt], bfrA, accA[rt][c], 0, 0, 0);
        accB[rt][c] = __builtin_amdgcn_mfma_f32_16x16x32_bf16(afr[rt], bfrB, accB[rt][c], 0, 0, 0);
      }
    }
  }
#pragma unroll
  for (int c = 0; c < 2; ++c) {
    const int col = w * 32 + c * 16 + l15;
    const float cA = bcA[col];
    const float dA = bdA[col];
    const float dB = bdB[col];
#pragma unroll
    for (int rt = 0; rt < 4; ++rt) {
#pragma unroll
      for (int r = 0; r < 4; ++r) {
        const int grow = r0 + rt * 16 + lg * 4 + r;
        const float dg = (float)deg[grow];
        outA[(size_t)grow * DF + col] = f2bf(accA[rt][c][r] + cA + dg * dA);
        outB[(size_t)grow * DF + col] = f2bf(accB[rt][c][r] + dg * dB);
      }
    }
  }
}

// Fused layer-2 edge kernel, 128 edges / 512 threads: two independent 64-edge
// halves, each running the r13-proven structure (stage h, msg GEMM, biased msg
// tile, f32x4 nt scatter, indicator-MFMA segment sums with boundary atomics).
// Waves 0-3: half 0 (rows 0-63); waves 4-7: half 1 (rows 64-127).
__global__ __launch_bounds__(512)
void edge_fused5(const unsigned short* __restrict__ A,
                 const unsigned short* __restrict__ B,
                 const int2* __restrict__ sorted_se,
                 const int* __restrict__ sorted_dst,
                 const unsigned short* __restrict__ w2p,
                 const float* __restrict__ b2,
                 float* __restrict__ msg_out,
                 float* __restrict__ feat_out) {
  __shared__ unsigned short h_s[EB * HS];
  __shared__ int node_s[EB];
  __shared__ int eid_s[EB];
  __shared__ unsigned char segid_s[EB];
  __shared__ int seg_node_s[2][64];
  __shared__ int nseg_s[2];
  const int t = threadIdx.x;
  const int e0 = blockIdx.x * EB;

  // ---- stage h: 4 threads/edge over 128 edges (proven pattern)
  {
    const int e = t >> 2, q = t & 3;
    const int pos = e0 + e;
    const int2 se = sorted_se[pos];
    const int di = sorted_dst[pos];
    if (q == 0) { node_s[e] = di; eid_s[e] = se.y; }
    const us8* ap = (const us8*)(A + (size_t)di * DF + q * 32);
    const us8* bp = (const us8*)(B + (size_t)se.x * DF + q * 32);
    us8 av[4], bv[4];
#pragma unroll
    for (int i = 0; i < 4; ++i) { av[i] = ap[i]; bv[i] = bp[i]; }
#pragma unroll
    for (int i = 0; i < 4; ++i) {
      us8 h;
#pragma unroll
      for (int j = 0; j < 8; ++j) {
        float v = bf2f(av[i][j]) + bf2f(bv[i][j]);
        v = v > 0.f ? v : 0.f;
        h[j] = f2bf(v);
      }
      *(us8*)&h_s[e * HS + q * 32 + i * 8] = h;
    }
  }
  __syncthreads();

  const int wv = t >> 6;          // wave 0..7
  const int hg = wv >> 2;         // half this wave works on
  const int cw = wv & 3;          // col group (32 cols)
  const int l = t & 63, l15 = l & 15, lg = l >> 4;
  const int rowbase = hg * 64;

  // ---- per-half segmentation (waves 0 and 4; segid includes own flag — r13 fix)
  if (cw == 0) {
    const int r = l;
    const int row = rowbase + r;
    const int flag = (r > 0 && node_s[row] != node_s[row - 1]) ? 1 : 0;
    const unsigned long long m = __ballot(flag);
    const int sid = (int)__popcll(m & ((1ull << r) - 1ull)) + flag;
    segid_s[row] = (unsigned char)sid;
    if (flag || r == 0) seg_node_s[hg][sid] = node_s[row];
    if (r == 63) nseg_s[hg] = sid + 1;
  }

  // ---- GEMM: msg = h @ W21 for this wave's half/cols (proven)
  f32x4 acc[4][2] = {};
  const uint4v* wvp = (const uint4v*)w2p;
#pragma unroll
  for (int kc = 0; kc < 4; ++kc) {
    bf16x8 afr[4];
#pragma unroll
    for (int rt = 0; rt < 4; ++rt)
      afr[rt] = __builtin_bit_cast(bf16x8,
          *(const uint4v*)&h_s[(rowbase + rt * 16 + l15) * HS + kc * 32 + lg * 8]);
#pragma unroll
    for (int c = 0; c < 2; ++c) {
      bf16x8 bfr = __builtin_bit_cast(bf16x8, wvp[((cw * 2 + c) * 4 + kc) * 64 + l]);
#pragma unroll
      for (int rt = 0; rt < 4; ++rt)
        acc[rt][c] = __builtin_amdgcn_mfma_f32_16x16x32_bf16(afr[rt], bfr, acc[rt][c], 0, 0, 0);
    }
  }
  __syncthreads();   // GEMM reads of h_s done; segmentation visible to all

  // ---- overwrite h_s with biased msg tile (bf16)
#pragma unroll
  for (int c = 0; c < 2; ++c) {
    const int col = cw * 32 + c * 16 + l15;
    const float bv = b2[col];
#pragma unroll
    for (int rt = 0; rt < 4; ++rt) {
#pragma unroll
      for (int r = 0; r < 4; ++r)
        h_s[(rowbase + rt * 16 + lg * 4 + r) * HS + col] = f2bf(acc[rt][c][r] + bv);
    }
  }
  __syncthreads();

  // ---- scatter msg rows (orig eid, row-coalesced f32x4 nt); 512 threads, 128 rows
  {
    const int off = (t & 31) * 4;
    const int rbase = t >> 5;            // 0..15
#pragma unroll
    for (int p = 0; p < 8; ++p) {
      const int row = p * 16 + rbase;
      us4 hv = *(const us4*)&h_s[row * HS + off];
      f32x4 o = { bf2f(hv[0]), bf2f(hv[1]), bf2f(hv[2]), bf2f(hv[3]) };
      __builtin_nontemporal_store(o, (f32x4*)(msg_out + (size_t)eid_s[row] * DF + off));
    }
  }

  // ---- feat2: per-half segment sums via indicator MFMA (proven r13)
  const int nseg = nseg_s[hg];
  // half boundaries: half0 prev = global prev block; half0 next = node_s[64].
  // half1 prev = node_s[63]; half1 next = next block's first dst.
  const int prevN = (hg == 0)
      ? ((e0 > 0) ? sorted_dst[e0 - 1] : -1)
      : node_s[63];
  const int nextN = (hg == 0)
      ? node_s[64]
      : ((e0 + EB < N_EDGES) ? sorted_dst[e0 + EB] : -1);
  if (nseg <= 32) {
    f32x4 sacc[2][2] = {};
#pragma unroll
    for (int kc = 0; kc < 2; ++kc) {
      bf16x8 ifr[2];
#pragma unroll
      for (int st = 0; st < 2; ++st) {
        const int srow = st * 16 + l15;
#pragma unroll
        for (int j = 0; j < 8; ++j)
          ifr[st][j] = (segid_s[rowbase + kc * 32 + lg * 8 + j] == srow)
                           ? (__bf16)1.0f : (__bf16)0.0f;
      }
#pragma unroll
      for (int c = 0; c < 2; ++c) {
        const int col = cw * 32 + c * 16 + l15;
        bf16x8 hfr;
#pragma unroll
        for (int j = 0; j < 8; ++j)
          hfr[j] = *(const __bf16*)&h_s[(rowbase + kc * 32 + lg * 8 + j) * HS + col];
#pragma unroll
        for (int st = 0; st < 2; ++st)
          sacc[st][c] = __builtin_amdgcn_mfma_f32_16x16x32_bf16(ifr[st], hfr, sacc[st][c], 0, 0, 0);
      }
    }
    const bool prevSame = prevN == node_s[rowbase];
    const bool nextSame = nextN == node_s[rowbase + 63];
#pragma unroll
    for (int st = 0; st < 2; ++st) {
#pragma unroll
      for (int c = 0; c < 2; ++c) {
        const int col = cw * 32 + c * 16 + l15;
#pragma unroll
        for (int r = 0; r < 4; ++r) {
          const int s = st * 16 + lg * 4 + r;
          if (s < nseg) {
            float* p = &feat_out[(size_t)seg_node_s[hg][s] * DF + col];
            const float v = sacc[st][c][r];
            const bool bd = (s == 0 && prevSame) || (s == nseg - 1 && nextSame);
            if (bd) unsafeAtomicAdd(p, v);
            else __builtin_nontemporal_store(v, p);
          }
        }
      }
    }
  } else {
    // all-atomic scalar fallback for this half (correctness only)
    const int tg = t & 255;
    if (tg < 128) {
      const int col = tg;
      float racc = 0.f;
      int run_n = node_s[rowbase];
      for (int r = 0; r < 64; ++r) {
        const int n = node_s[rowbase + r];
        if (n != run_n) {
          unsafeAtomicAdd(&feat_out[(size_t)run_n * DF + col], racc);
          run_n = n; racc = 0.f;
        }
        racc += bf2f(h_s[(rowbase + r) * HS + col]);
      }
      unsafeAtomicAdd(&feat_out[(size_t)run_n * DF + col], racc);
    }
  }
}

extern "C" void kernel_launch(void* const* d_in, const int* in_sizes, int n_in,
                              void* d_out, int out_size, void* d_ws, size_t ws_size,
                              hipStream_t stream) {
  const float* x    = (const float*)d_in[0];
  const int*   eidx = (const int*)d_in[1];
  const float* W1_0 = (const float*)d_in[2];
  const float* b1_0 = (const float*)d_in[3];
  const float* W2_0 = (const float*)d_in[4];
  const float* b2_0 = (const float*)d_in[5];
  const float* W1_1 = (const float*)d_in[6];
  const float* b1_1 = (const float*)d_in[7];
  const float* W2_1 = (const float*)d_in[8];
  const float* b2_1 = (const float*)d_in[9];

  const int* src = eidx;
  const int* dst = eidx + N_EDGES;

  float* feat2 = (float*)d_out;
  float* msg2  = feat2 + (size_t)N_NODES * DF;

  // ---- workspace layout (~62 MB; 8-B arrays first for alignment) ----
  char* ws = (char*)d_ws;
  const size_t BF_ROWS = (size_t)N_PAD * DF;
  unsigned short* A1 = (unsigned short*)ws;  ws += BF_ROWS * 2;   // 12.8 MB
  unsigned short* B1 = (unsigned short*)ws;  ws += BF_ROWS * 2;   // 12.8 MB
  unsigned short* A2 = (unsigned short*)ws;  ws += BF_ROWS * 2;   // 12.8 MB
  unsigned short* B2 = (unsigned short*)ws;  ws += BF_ROWS * 2;   // 12.8 MB
  int2* sorted_se = (int2*)ws; ws += (size_t)N_EDGES * 8;         // 6.4 MB
  int* sorted_dst = (int*)ws;  ws += (size_t)N_EDGES * 4;         // 3.2 MB
  int* deg        = (int*)ws;  ws += (size_t)N_PAD * 4;
  int* row_ptr    = (int*)ws;  ws += (size_t)(N_PAD + 1) * 4;
  int* cursor     = (int*)ws;  ws += (size_t)N_PAD * 4;
  float* vA     = (float*)ws;  ws += 128 * 4;
  float* vB     = (float*)ws;  ws += 128 * 4;
  unsigned short* wa1p  = (unsigned short*)ws;  ws += 16384 * 2;
  unsigned short* wb1p  = (unsigned short*)ws;  ws += 16384 * 2;
  unsigned short* w21p  = (unsigned short*)ws;  ws += 16384 * 2;
  unsigned short* w20Ap = (unsigned short*)ws;  ws += 16384 * 2;
  unsigned short* w20Bp = (unsigned short*)ws;  ws += 16384 * 2;

  hipMemsetAsync(deg, 0, (size_t)N_PAD * 4, stream);
  // feat2 zero-init: boundary segments atomicAdd onto it; deg-0 nodes stay 0.
  hipMemsetAsync(feat2, 0, (size_t)N_NODES * DF * 4, stream);

  // Fused weight prep (wcomb direct-packed + 3 packs) + deg histogram.
  wprep_deg<<<153 + DEG_BLOCKS, 256, 0, stream>>>(
      W2_0, W1_1, b2_0, W1_0, W2_1,
      w20Ap, w20Bp, vA, vB, wa1p, wb1p, w21p, dst, deg);

  // Fat: scan (block 0) + layer-1 dual GEMM (blocks 1..NG).
  scan_gemm1<<<1 + NG, 256, 0, stream>>>(deg, row_ptr, cursor,
                                         x, wa1p, wb1p, b1_0, A1, B1);

  sort_kernel<<<DEG_BLOCKS, 256, 0, stream>>>(src, dst, cursor,
                                              sorted_se, sorted_dst);

  // Fused aggregate(Hsum1) + combined-weight dual GEMM -> A2, B2
  agg_dual<<<NG, 256, 0, stream>>>(A1, B1, row_ptr, sorted_se,
                                   w20Ap, w20Bp, b1_1, vA, vB, deg, A2, B2);

  // Fused: msg2 (f32x4 nt scatter) + feat2 (indicator-MFMA segment sums)
  edge_fused5<<<N_EDGES / EB, 512, 0, stream>>>(A2, B2, sorted_se, sorted_dst,
                                                w21p, b2_1, msg2, feat2);
}

// Round 15
// 418.535 us; speedup vs baseline: 1.0165x; 1.0165x over previous
//
#include <hip/hip_runtime.h>
#include <hip/hip_bf16.h>

#define N_NODES 50000
#define N_PAD   50048      // 64-row multiple for guard-free GEMM tiles
#define N_EDGES 800000
#define DF 128
#define NG (N_PAD / 64)    // 782 node-GEMM blocks
#define DEG_BLOCKS (N_EDGES / 256)  // 3125

// LDS row stride (ushorts): 128 bf16 + 8 pad (272 B = 17*16 B)
#define HS 136

typedef __bf16 bf16x8 __attribute__((ext_vector_type(8)));
typedef float f32x4 __attribute__((ext_vector_type(4)));
typedef unsigned int uint4v __attribute__((ext_vector_type(4)));
typedef unsigned short us4 __attribute__((ext_vector_type(4)));
typedef unsigned short us8 __attribute__((ext_vector_type(8)));

__device__ __forceinline__ unsigned short f2bf(float f) {
  unsigned u = __builtin_bit_cast(unsigned, f);
  u += 0x7FFFu + ((u >> 16) & 1u);   // RNE
  return (unsigned short)(u >> 16);
}
__device__ __forceinline__ float bf2f(unsigned short u) {
  return __builtin_bit_cast(float, ((unsigned)u) << 16);
}

// Packed-fragment offset for element (k,col) of a [128][128] matrix.
__device__ __forceinline__ int pack_off(int k, int c) {
  return ((((c >> 4) * 4 + (k >> 5)) * 64) + ((k >> 3) & 3) * 16 + (c & 15)) * 8
         + (k & 7);
}

// ---------------- fused weight prep + deg histogram (proven r10) ----------------
__global__ __launch_bounds__(256)
void wprep_deg(const float* __restrict__ W2_0,
               const float* __restrict__ W1_1,
               const float* __restrict__ b2_0,
               const float* __restrict__ W1_0,
               const float* __restrict__ W2_1,
               unsigned short* __restrict__ w20Ap,
               unsigned short* __restrict__ w20Bp,
               float* __restrict__ vA,
               float* __restrict__ vB,
               unsigned short* __restrict__ wa1p,
               unsigned short* __restrict__ wb1p,
               unsigned short* __restrict__ w21p,
               const int* __restrict__ dst,
               int* __restrict__ deg) {
  const int b = blockIdx.x;
  const int t = threadIdx.x;

  if (b < 129) {                      // wcomb, direct-packed
    const int c = t & 127;
    const bool isB = t >= 128;
    float acc = 0.f;
    if (b < 128) {
      const float* wrow = W2_0 + (size_t)b * DF;
      for (int k = 0; k < 128; ++k) {
        float bot = W1_1[(size_t)(128 + k) * DF + c];
        float w = isB ? bot : (W1_1[(size_t)k * DF + c] - bot);
        acc += wrow[k] * w;
      }
      unsigned short* out = isB ? w20Bp : w20Ap;
      out[pack_off(b, c)] = f2bf(acc);
    } else {
      for (int k = 0; k < 128; ++k) {
        float bot = W1_1[(size_t)(128 + k) * DF + c];
        float w = isB ? bot : (W1_1[(size_t)k * DF + c] - bot);
        acc += b2_0[k] * w;
      }
      if (isB) vB[c] = acc;
      else     vA[c] = acc;
    }
    return;
  }

  if (b < 153) {                      // pack wa1p / wb1p / w21p
    const int mat = (b - 129) >> 3;
    const int idx = ((b - 129) & 7) * 256 + t;   // < 2048
    const int l = idx & 63;
    const int blk = idx >> 6;
    const int ct = blk >> 2;
    const int kc = blk & 3;
    const int col = ct * 16 + (l & 15);
    const int k0 = kc * 32 + (l >> 4) * 8;
    const float* W;
    const float* Wsub = nullptr;
    unsigned short* out;
    if (mat == 0)      { W = W1_0;            Wsub = W1_0 + 128 * DF; out = wa1p; }
    else if (mat == 1) { W = W1_0 + 128 * DF;                         out = wb1p; }
    else               { W = W2_1;                                    out = w21p; }
    unsigned short tmp[8];
#pragma unroll
    for (int j = 0; j < 8; ++j) {
      float v = W[(size_t)(k0 + j) * DF + col];
      if (Wsub) v -= Wsub[(size_t)(k0 + j) * DF + col];
      tmp[j] = f2bf(v);
    }
    us4 lo = { tmp[0], tmp[1], tmp[2], tmp[3] };
    us4 hi = { tmp[4], tmp[5], tmp[6], tmp[7] };
    us4* o = (us4*)(out + (size_t)idx * 8);
    o[0] = lo;
    o[1] = hi;
    return;
  }

  // deg histogram
  const int e = (b - 153) * 256 + t;
  if (e < N_EDGES) atomicAdd(&deg[dst[e]], 1);
}

// ---------------- CSR sort: packed (src,eid) + dst (proven r12) ----------------
__global__ void sort_kernel(const int* __restrict__ src,
                            const int* __restrict__ dst,
                            int* __restrict__ cursor,
                            int2* __restrict__ sorted_se,
                            int* __restrict__ sorted_dst) {
  const int e = blockIdx.x * 256 + threadIdx.x;
  const int d = dst[e];
  const int pos = atomicAdd(&cursor[d], 1);
  sorted_se[pos] = make_int2(src[e], e);
  sorted_dst[pos] = d;
}

// ---------------- shared device pieces (proven r12) ----------------
__device__ __forceinline__ void agg_phase(const unsigned short* __restrict__ A,
                                          const unsigned short* __restrict__ B,
                                          const int* __restrict__ row_ptr,
                                          const int2* __restrict__ sorted_se,
                                          unsigned short* xs, int r0, int t) {
  const int w = t >> 6, l = t & 63;
  const int lane16 = l & 15;
  const int g = l >> 4;
#pragma unroll
  for (int i = 0; i < 4; ++i) {
    const int nl = w * 16 + i * 4 + g;       // 0..63
    const int n = r0 + nl;
    const int beg = row_ptr[n];
    const int end = row_ptr[n + 1];
    us8 av = *(const us8*)(A + (size_t)n * DF + lane16 * 8);
    float af[8];
#pragma unroll
    for (int j = 0; j < 8; ++j) af[j] = bf2f(av[j]);
    float acc[8] = {};
    int k = beg;
    for (; k + 8 <= end; k += 8) {
      us8 bv[8];
#pragma unroll
      for (int u = 0; u < 8; ++u) {
        const int s = sorted_se[k + u].x;
        bv[u] = *(const us8*)(B + (size_t)s * DF + lane16 * 8);
      }
#pragma unroll
      for (int j = 0; j < 8; ++j) {
#pragma unroll
        for (int u = 0; u < 8; ++u) {
          float v = af[j] + bf2f(bv[u][j]);
          acc[j] += v > 0.f ? v : 0.f;
        }
      }
    }
    for (; k < end; ++k) {
      const int s = sorted_se[k].x;
      us8 bv = *(const us8*)(B + (size_t)s * DF + lane16 * 8);
#pragma unroll
      for (int j = 0; j < 8; ++j) {
        float v = af[j] + bf2f(bv[j]);
        acc[j] += v > 0.f ? v : 0.f;
      }
    }
    us8 o;
#pragma unroll
    for (int j = 0; j < 8; ++j) o[j] = f2bf(acc[j]);
    *(us8*)&xs[nl * HS + lane16 * 8] = o;
  }
}

// ---------------- kernels ----------------

// Fat kernel: block 0 = scan; blocks 1..NG = layer-1 dual GEMM (proven r10).
#define SCH ((N_PAD + 255) / 256)   // 196
__global__ __launch_bounds__(256)
void scan_gemm1(const int* __restrict__ deg,
                int* __restrict__ row_ptr,
                int* __restrict__ cursor,
                const float* __restrict__ in,
                const unsigned short* __restrict__ wpA,
                const unsigned short* __restrict__ wpB,
                const float* __restrict__ bcA,
                unsigned short* __restrict__ outA,
                unsigned short* __restrict__ outB) {
  __shared__ unsigned short xs[64 * HS];
  const int t = threadIdx.x;

  if (blockIdx.x == 0) {
    int* part = (int*)xs;
    const int lo = t * SCH;
    const int hi = min(lo + SCH, N_PAD);
    int s = 0;
    for (int i = lo; i < hi; ++i) s += deg[i];
    part[t] = s;
    __syncthreads();
    for (int off = 1; off < 256; off <<= 1) {
      int v = (t >= off) ? part[t - off] : 0;
      __syncthreads();
      part[t] += v;
      __syncthreads();
    }
    int run = (t > 0) ? part[t - 1] : 0;
    for (int i = lo; i < hi; ++i) {
      row_ptr[i] = run;
      cursor[i] = run;
      run += deg[i];
    }
    if (t == 255) row_ptr[N_PAD] = part[255];
    return;
  }

  const int r0 = (blockIdx.x - 1) * 64;
  {
    const int e = t >> 2, q = t & 3;
    const int grow = r0 + e;
    const float4* src = (const float4*)(in + (size_t)grow * DF) + q * 8;
#pragma unroll
    for (int i = 0; i < 8; ++i) {
      float4 v = { 0.f, 0.f, 0.f, 0.f };
      if (grow < N_NODES) v = src[i];
      us4 p = { f2bf(v.x), f2bf(v.y), f2bf(v.z), f2bf(v.w) };
      *(us4*)&xs[e * HS + q * 32 + i * 4] = p;
    }
  }
  __syncthreads();

  const int w = t >> 6, l = t & 63, l15 = l & 15, lg = l >> 4;
  f32x4 accA[4][2] = {};
  f32x4 accB[4][2] = {};
  const uint4v* wvA = (const uint4v*)wpA;
  const uint4v* wvB = (const uint4v*)wpB;
#pragma unroll
  for (int kc = 0; kc < 4; ++kc) {
    bf16x8 afr[4];
#pragma unroll
    for (int rt = 0; rt < 4; ++rt)
      afr[rt] = __builtin_bit_cast(bf16x8,
          *(const uint4v*)&xs[(rt * 16 + l15) * HS + kc * 32 + lg * 8]);
#pragma unroll
    for (int c = 0; c < 2; ++c) {
      bf16x8 bfrA = __builtin_bit_cast(bf16x8, wvA[((w * 2 + c) * 4 + kc) * 64 + l]);
      bf16x8 bfrB = __builtin_bit_cast(bf16x8, wvB[((w * 2 + c) * 4 + kc) * 64 + l]);
#pragma unroll
      for (int rt = 0; rt < 4; ++rt) {
        accA[rt][c] = __builtin_amdgcn_mfma_f32_16x16x32_bf16(afr[rt], bfrA, accA[rt][c], 0, 0, 0);
        accB[rt][c] = __builtin_amdgcn_mfma_f32_16x16x32_bf16(afr[rt], bfrB, accB[rt][c], 0, 0, 0);
      }
    }
  }
#pragma unroll
  for (int c = 0; c < 2; ++c) {
    const int col = w * 32 + c * 16 + l15;
    const float cA = bcA[col];
#pragma unroll
    for (int rt = 0; rt < 4; ++rt) {
#pragma unroll
      for (int r = 0; r < 4; ++r) {
        const int grow = r0 + rt * 16 + lg * 4 + r;
        outA[(size_t)grow * DF + col] = f2bf(accA[rt][c][r] + cA);
        outB[(size_t)grow * DF + col] = f2bf(accB[rt][c][r]);
      }
    }
  }
}

// Fused: Hsum1 aggregation (LDS) + combined-weight dual GEMM -> A2, B2 (proven)
__global__ __launch_bounds__(256)
void agg_dual(const unsigned short* __restrict__ A,
              const unsigned short* __restrict__ B,
              const int* __restrict__ row_ptr,
              const int2* __restrict__ sorted_se,
              const unsigned short* __restrict__ wpA,
              const unsigned short* __restrict__ wpB,
              const float* __restrict__ bcA, const float* __restrict__ bdA,
              const float* __restrict__ bdB,
              const int* __restrict__ deg,
              unsigned short* __restrict__ outA,
              unsigned short* __restrict__ outB) {
  __shared__ unsigned short xs[64 * HS];
  const int t = threadIdx.x;
  const int r0 = blockIdx.x * 64;

  agg_phase(A, B, row_ptr, sorted_se, xs, r0, t);
  __syncthreads();

  const int w = t >> 6, l = t & 63, l15 = l & 15, lg = l >> 4;
  f32x4 accA[4][2] = {};
  f32x4 accB[4][2] = {};
  const uint4v* wvA = (const uint4v*)wpA;
  const uint4v* wvB = (const uint4v*)wpB;
#pragma unroll
  for (int kc = 0; kc < 4; ++kc) {
    bf16x8 afr[4];
#pragma unroll
    for (int rt = 0; rt < 4; ++rt)
      afr[rt] = __builtin_bit_cast(bf16x8,
          *(const uint4v*)&xs[(rt * 16 + l15) * HS + kc * 32 + lg * 8]);
#pragma unroll
    for (int c = 0; c < 2; ++c) {
      bf16x8 bfrA = __builtin_bit_cast(bf16x8, wvA[((w * 2 + c) * 4 + kc) * 64 + l]);
      bf16x8 bfrB = __builtin_bit_cast(bf16x8, wvB[((w * 2 + c) * 4 + kc) * 64 + l]);
#pragma unroll
      for (int rt = 0; rt < 4; ++rt) {
        accA[rt][c] = __builtin_amdgcn_mfma_f32_16x16x32_bf16(afr[rt], bfrA, accA[rt][c], 0, 0, 0);
        accB[rt][c] = __builtin_amdgcn_mfma_f32_16x16x32_bf16(afr[rt], bfrB, accB[rt][c], 0, 0, 0);
      }
    }
  }
#pragma unroll
  for (int c = 0; c < 2; ++c) {
    const int col = w * 32 + c * 16 + l15;
    const float cA = bcA[col];
    const float dA = bdA[col];
    const float dB = bdB[col];
#pragma unroll
    for (int rt = 0; rt < 4; ++rt) {
#pragma unroll
      for (int r = 0; r < 4; ++r) {
        const int grow = r0 + rt * 16 + lg * 4 + r;
        const float dg = (float)deg[grow];
        outA[(size_t)grow * DF + col] = f2bf(accA[rt][c][r] + cA + dg * dA);
        outB[(size_t)grow * DF + col] = f2bf(accB[rt][c][r] + dg * dB);
      }
    }
  }
}

// Fused layer-2 edge kernel: h = relu(A2[dst]+B2[src]); msg = h@W21 + b2_1;
// msg tile (bf16) -> LDS; f32x4 nt scatter to msg[orig eid]; feat2 = segment
// sums of the biased msg tile via indicator-matrix MFMA (segid includes own
// flag). Boundary segments atomic.
__global__ __launch_bounds__(256)
void edge_fused4(const unsigned short* __restrict__ A,
                 const unsigned short* __restrict__ B,
                 const int2* __restrict__ sorted_se,
                 const int* __restrict__ sorted_dst,
                 const unsigned short* __restrict__ w2p,
                 const float* __restrict__ b2,
                 float* __restrict__ msg_out,
                 float* __restrict__ feat_out) {
  __shared__ unsigned short h_s[64 * HS];
  __shared__ int node_s[64];
  __shared__ int eid_s[64];
  __shared__ unsigned char segid_s[64];
  __shared__ int seg_node_s[64];
  __shared__ int nseg_s;
  const int t = threadIdx.x;
  const int e0 = blockIdx.x * 64;

  // ---- stage h (proven)
  {
    const int e = t >> 2, q = t & 3;
    const int pos = e0 + e;
    const int2 se = sorted_se[pos];
    const int di = sorted_dst[pos];
    if (q == 0) { node_s[e] = di; eid_s[e] = se.y; }
    const us8* ap = (const us8*)(A + (size_t)di * DF + q * 32);
    const us8* bp = (const us8*)(B + (size_t)se.x * DF + q * 32);
    us8 av[4], bv[4];
#pragma unroll
    for (int i = 0; i < 4; ++i) { av[i] = ap[i]; bv[i] = bp[i]; }
#pragma unroll
    for (int i = 0; i < 4; ++i) {
      us8 h;
#pragma unroll
      for (int j = 0; j < 8; ++j) {
        float v = bf2f(av[i][j]) + bf2f(bv[i][j]);
        v = v > 0.f ? v : 0.f;
        h[j] = f2bf(v);
      }
      *(us8*)&h_s[e * HS + q * 32 + i * 8] = h;
    }
  }
  __syncthreads();

  // ---- segmentation (wave 0; segid INCLUDES own flag)
  if (t < 64) {
    const int flag = (t > 0 && node_s[t] != node_s[t - 1]) ? 1 : 0;
    const unsigned long long m = __ballot(flag);
    const int sid = (int)__popcll(m & ((1ull << t) - 1ull)) + flag;
    segid_s[t] = (unsigned char)sid;
    if (flag || t == 0) seg_node_s[sid] = node_s[t];
    if (t == 63) nseg_s = sid + 1;
  }

  const int w = t >> 6, l = t & 63, l15 = l & 15, lg = l >> 4;

  // ---- GEMM: msg = h @ W21 (proven)
  f32x4 acc[4][2] = {};
  const uint4v* wv = (const uint4v*)w2p;
#pragma unroll
  for (int kc = 0; kc < 4; ++kc) {
    bf16x8 afr[4];
#pragma unroll
    for (int rt = 0; rt < 4; ++rt)
      afr[rt] = __builtin_bit_cast(bf16x8,
          *(const uint4v*)&h_s[(rt * 16 + l15) * HS + kc * 32 + lg * 8]);
#pragma unroll
    for (int c = 0; c < 2; ++c) {
      bf16x8 bfr = __builtin_bit_cast(bf16x8, wv[((w * 2 + c) * 4 + kc) * 64 + l]);
#pragma unroll
      for (int rt = 0; rt < 4; ++rt)
        acc[rt][c] = __builtin_amdgcn_mfma_f32_16x16x32_bf16(afr[rt], bfr, acc[rt][c], 0, 0, 0);
    }
  }
  __syncthreads();   // GEMM reads of h_s done; segmentation visible to all

  // ---- overwrite h_s with biased msg tile (bf16)
#pragma unroll
  for (int c = 0; c < 2; ++c) {
    const int col = w * 32 + c * 16 + l15;
    const float bv = b2[col];
#pragma unroll
    for (int rt = 0; rt < 4; ++rt) {
#pragma unroll
      for (int r = 0; r < 4; ++r)
        h_s[(rt * 16 + lg * 4 + r) * HS + col] = f2bf(acc[rt][c][r] + bv);
    }
  }
  __syncthreads();

  // ---- scatter msg rows (orig eid, row-coalesced f32x4 nt)
  {
    const int off = (t & 31) * 4;
    const int rbase = t >> 5;
#pragma unroll
    for (int p = 0; p < 8; ++p) {
      const int row = p * 8 + rbase;
      us4 hv = *(const us4*)&h_s[row * HS + off];
      f32x4 o = { bf2f(hv[0]), bf2f(hv[1]), bf2f(hv[2]), bf2f(hv[3]) };
      __builtin_nontemporal_store(o, (f32x4*)(msg_out + (size_t)eid_s[row] * DF + off));
    }
  }

  // ---- feat2: segment sums S = I(32seg x 64edge) @ msg(64 x 128) via MFMA
  const int nseg = nseg_s;
  if (nseg <= 32) {
    f32x4 sacc[2][2] = {};
#pragma unroll
    for (int kc = 0; kc < 2; ++kc) {
      bf16x8 ifr[2];
#pragma unroll
      for (int st = 0; st < 2; ++st) {
        const int srow = st * 16 + l15;
#pragma unroll
        for (int j = 0; j < 8; ++j)
          ifr[st][j] = (segid_s[kc * 32 + lg * 8 + j] == srow) ? (__bf16)1.0f
                                                               : (__bf16)0.0f;
      }
#pragma unroll
      for (int c = 0; c < 2; ++c) {
        const int col = w * 32 + c * 16 + l15;
        bf16x8 hfr;
#pragma unroll
        for (int j = 0; j < 8; ++j)
          hfr[j] = *(const __bf16*)&h_s[(kc * 32 + lg * 8 + j) * HS + col];
#pragma unroll
        for (int st = 0; st < 2; ++st)
          sacc[st][c] = __builtin_amdgcn_mfma_f32_16x16x32_bf16(ifr[st], hfr, sacc[st][c], 0, 0, 0);
      }
    }
    const bool prevSame = (blockIdx.x > 0) && (sorted_dst[e0 - 1] == node_s[0]);
    const bool nextSame = (e0 + 64 < N_EDGES) && (sorted_dst[e0 + 64] == node_s[63]);
#pragma unroll
    for (int st = 0; st < 2; ++st) {
#pragma unroll
      for (int c = 0; c < 2; ++c) {
        const int col = w * 32 + c * 16 + l15;
#pragma unroll
        for (int r = 0; r < 4; ++r) {
          const int s = st * 16 + lg * 4 + r;
          if (s < nseg) {
            float* p = &feat_out[(size_t)seg_node_s[s] * DF + col];
            const float v = sacc[st][c][r];
            const bool bd = (s == 0 && prevSame) || (s == nseg - 1 && nextSame);
            if (bd) unsafeAtomicAdd(p, v);
            else __builtin_nontemporal_store(v, p);
          }
        }
      }
    }
  } else {
    // all-atomic scalar fallback (correctness only; nseg>32 ~ impossible)
    const int col = t & 127;
    const int rbeg = (t >> 7) * 32, rend = rbeg + 32;
    float racc = 0.f;
    int run_n = node_s[rbeg];
    for (int r = rbeg; r < rend; ++r) {
      const int n = node_s[r];
      if (n != run_n) {
        unsafeAtomicAdd(&feat_out[(size_t)run_n * DF + col], racc);
        run_n = n; racc = 0.f;
      }
      racc += bf2f(h_s[r * HS + col]);
    }
    unsafeAtomicAdd(&feat_out[(size_t)run_n * DF + col], racc);
  }
}

extern "C" void kernel_launch(void* const* d_in, const int* in_sizes, int n_in,
                              void* d_out, int out_size, void* d_ws, size_t ws_size,
                              hipStream_t stream) {
  const float* x    = (const float*)d_in[0];
  const int*   eidx = (const int*)d_in[1];
  const float* W1_0 = (const float*)d_in[2];
  const float* b1_0 = (const float*)d_in[3];
  const float* W2_0 = (const float*)d_in[4];
  const float* b2_0 = (const float*)d_in[5];
  const float* W1_1 = (const float*)d_in[6];
  const float* b1_1 = (const float*)d_in[7];
  const float* W2_1 = (const float*)d_in[8];
  const float* b2_1 = (const float*)d_in[9];

  const int* src = eidx;
  const int* dst = eidx + N_EDGES;

  float* feat2 = (float*)d_out;
  float* msg2  = feat2 + (size_t)N_NODES * DF;

  // ---- workspace layout (~62 MB; 8-B arrays first for alignment) ----
  char* ws = (char*)d_ws;
  const size_t BF_ROWS = (size_t)N_PAD * DF;
  unsigned short* A1 = (unsigned short*)ws;  ws += BF_ROWS * 2;   // 12.8 MB
  unsigned short* B1 = (unsigned short*)ws;  ws += BF_ROWS * 2;   // 12.8 MB
  unsigned short* A2 = (unsigned short*)ws;  ws += BF_ROWS * 2;   // 12.8 MB
  unsigned short* B2 = (unsigned short*)ws;  ws += BF_ROWS * 2;   // 12.8 MB
  int2* sorted_se = (int2*)ws; ws += (size_t)N_EDGES * 8;         // 6.4 MB
  int* sorted_dst = (int*)ws;  ws += (size_t)N_EDGES * 4;         // 3.2 MB
  int* deg        = (int*)ws;  ws += (size_t)N_PAD * 4;
  int* row_ptr    = (int*)ws;  ws += (size_t)(N_PAD + 1) * 4;
  int* cursor     = (int*)ws;  ws += (size_t)N_PAD * 4;
  float* vA     = (float*)ws;  ws += 128 * 4;
  float* vB     = (float*)ws;  ws += 128 * 4;
  unsigned short* wa1p  = (unsigned short*)ws;  ws += 16384 * 2;
  unsigned short* wb1p  = (unsigned short*)ws;  ws += 16384 * 2;
  unsigned short* w21p  = (unsigned short*)ws;  ws += 16384 * 2;
  unsigned short* w20Ap = (unsigned short*)ws;  ws += 16384 * 2;
  unsigned short* w20Bp = (unsigned short*)ws;  ws += 16384 * 2;

  hipMemsetAsync(deg, 0, (size_t)N_PAD * 4, stream);
  // feat2 zero-init: boundary segments atomicAdd onto it; deg-0 nodes stay 0.
  hipMemsetAsync(feat2, 0, (size_t)N_NODES * DF * 4, stream);

  // Fused weight prep (wcomb direct-packed + 3 packs) + deg histogram.
  wprep_deg<<<153 + DEG_BLOCKS, 256, 0, stream>>>(
      W2_0, W1_1, b2_0, W1_0, W2_1,
      w20Ap, w20Bp, vA, vB, wa1p, wb1p, w21p, dst, deg);

  // Fat: scan (block 0) + layer-1 dual GEMM (blocks 1..NG).
  scan_gemm1<<<1 + NG, 256, 0, stream>>>(deg, row_ptr, cursor,
                                         x, wa1p, wb1p, b1_0, A1, B1);

  sort_kernel<<<DEG_BLOCKS, 256, 0, stream>>>(src, dst, cursor,
                                              sorted_se, sorted_dst);

  // Fused aggregate(Hsum1) + combined-weight dual GEMM -> A2, B2
  agg_dual<<<NG, 256, 0, stream>>>(A1, B1, row_ptr, sorted_se,
                                   w20Ap, w20Bp, b1_1, vA, vB, deg, A2, B2);

  // Fused: msg2 (f32x4 nt scatter) + feat2 (indicator-MFMA segment sums)
  edge_fused4<<<N_EDGES / 64, 256, 0, stream>>>(A2, B2, sorted_se, sorted_dst,
                                                w21p, b2_1, msg2, feat2);
}